// Round 1
// baseline (1290.686 us; speedup 1.0000x reference)
//
#include <hip/hip_runtime.h>
#include <math.h>

#define N_NODES 100000
#define N_EDGES 3200000
#define N_GRAPHS 64
#define IN_DIM 128
#define HID 64
#define BN_EPS 1e-5f

#define SCAN_CHUNK 1024
#define NBLK_SCAN ((N_NODES + SCAN_CHUNK - 1) / SCAN_CHUNK)  // 98
#define BN_BLOCKS 256

// ---------------- degree / CSR build ----------------

__global__ void count_deg_k(const int* __restrict__ ei, int* __restrict__ deg) {
  int e = blockIdx.x * blockDim.x + threadIdx.x;
  if (e < N_EDGES) atomicAdd(&deg[ei[N_EDGES + e]], 1);
}

__global__ void dinv_k(const int* __restrict__ deg, float* __restrict__ dinv) {
  int n = blockIdx.x * blockDim.x + threadIdx.x;
  if (n < N_NODES) dinv[n] = rsqrtf((float)(deg[n] + 1));  // +1 self loop
}

__global__ __launch_bounds__(256) void scan_a_k(const int* __restrict__ deg,
                                                int* __restrict__ bsum) {
  int t = threadIdx.x;
  int base = blockIdx.x * SCAN_CHUNK;
  int s = 0;
  for (int p = 0; p < 4; ++p) {
    int i = base + t + p * 256;
    if (i < N_NODES) s += deg[i];
  }
  __shared__ int red[256];
  red[t] = s; __syncthreads();
  for (int o = 128; o > 0; o >>= 1) {
    if (t < o) red[t] += red[t + o];
    __syncthreads();
  }
  if (t == 0) bsum[blockIdx.x] = red[0];
}

__global__ void scan_b_k(int* bsum) {
  __shared__ int sa[128], sb[128];
  int t = threadIdx.x;
  int* src = sa; int* dst = sb;
  sa[t] = (t < NBLK_SCAN) ? bsum[t] : 0;
  __syncthreads();
  for (int o = 1; o < 128; o <<= 1) {
    dst[t] = src[t] + ((t >= o) ? src[t - o] : 0);
    __syncthreads();
    int* tmp = src; src = dst; dst = tmp;
  }
  if (t < NBLK_SCAN) bsum[t] = (t == 0) ? 0 : src[t - 1];
}

__global__ __launch_bounds__(256) void scan_c_k(const int* __restrict__ deg,
                                                const int* __restrict__ bsum,
                                                int* __restrict__ rowptr) {
  int t = threadIdx.x;
  int base = blockIdx.x * SCAN_CHUNK;
  int i0 = base + t * 4;
  int v[4];
#pragma unroll
  for (int q = 0; q < 4; ++q) v[q] = (i0 + q < N_NODES) ? deg[i0 + q] : 0;
  int tsum = v[0] + v[1] + v[2] + v[3];
  __shared__ int sa[256], sb[256];
  int* src = sa; int* dst = sb;
  sa[t] = tsum;
  __syncthreads();
  for (int o = 1; o < 256; o <<= 1) {
    dst[t] = src[t] + ((t >= o) ? src[t - o] : 0);
    __syncthreads();
    int* tmp = src; src = dst; dst = tmp;
  }
  int run = bsum[blockIdx.x] + src[t] - tsum;  // exclusive prefix
#pragma unroll
  for (int q = 0; q < 4; ++q) {
    if (i0 + q < N_NODES) rowptr[i0 + q] = run;
    run += v[q];
  }
}

__global__ void fill_csr_k(const int* __restrict__ ei, const int* __restrict__ rowptr,
                           int* __restrict__ cursor, int* __restrict__ csr) {
  int e = blockIdx.x * blockDim.x + threadIdx.x;
  if (e >= N_EDGES) return;
  int c = ei[N_EDGES + e];
  int r = ei[e];
  int p = atomicAdd(&cursor[c], 1);
  csr[rowptr[c] + p] = r;
}

// ---------------- GEMM: out[n][c] = sum_k in[n][k]*W[k][c], optional BN+ReLU on input ----------------
// Block: 256 threads, tile 64 rows x 64 cols. Thread (tc=tid&15, tr=tid>>4)
// computes rows 4*tr+i (i<4), cols tc+16*j (j<4).

template <int K, bool APPLY, bool RELU>
__global__ __launch_bounds__(256) void gemm_k(
    const float* __restrict__ X, const float* __restrict__ W,
    const float* __restrict__ scale, const float* __restrict__ shift,
    float* __restrict__ out, int nrows) {
  constexpr int WROW = K + 4;       // stride ≡ 4 (mod 32) -> 2-way max on b128 reads
  __shared__ float wt[64 * WROW];   // wt[c][k]  (W transposed)
  __shared__ float xs[64 * 68];     // xs[r][k] for current 64-wide k chunk
  const int tid = threadIdx.x;
  const int tc = tid & 15;
  const int tr = tid >> 4;

  for (int idx = tid; idx < K * 64; idx += 256) {
    int k = idx >> 6, c = idx & 63;
    wt[c * WROW + k] = W[idx];
  }

  const int rowbase = blockIdx.x * 64;
  float acc[4][4] = {};

  for (int kc = 0; kc < K; kc += 64) {
    __syncthreads();
    // stage 64 rows x 64 k of X (coalesced float4), fused BN apply
    {
      const int kq = tid & 15;
      const int rr = tid >> 4;
#pragma unroll
      for (int p = 0; p < 4; ++p) {
        int r = rr + p * 16;
        int grow = rowbase + r;
        float4 v = make_float4(0.f, 0.f, 0.f, 0.f);
        if (grow < nrows) v = *(const float4*)(X + (size_t)grow * K + kc + kq * 4);
        if (APPLY) {
          int kg = kc + kq * 4;
          float4 sc = *(const float4*)(scale + kg);
          float4 sh = *(const float4*)(shift + kg);
          v.x = v.x * sc.x + sh.x;
          v.y = v.y * sc.y + sh.y;
          v.z = v.z * sc.z + sh.z;
          v.w = v.w * sc.w + sh.w;
          if (RELU) {
            v.x = fmaxf(v.x, 0.f); v.y = fmaxf(v.y, 0.f);
            v.z = fmaxf(v.z, 0.f); v.w = fmaxf(v.w, 0.f);
          }
        }
        *(float4*)(xs + r * 68 + kq * 4) = v;
      }
    }
    __syncthreads();
#pragma unroll 4
    for (int k0 = 0; k0 < 64; k0 += 4) {
      float4 xv[4], wv[4];
#pragma unroll
      for (int i = 0; i < 4; ++i)
        xv[i] = *(const float4*)(xs + (tr * 4 + i) * 68 + k0);
#pragma unroll
      for (int j = 0; j < 4; ++j)
        wv[j] = *(const float4*)(wt + (tc + 16 * j) * WROW + kc + k0);
#pragma unroll
      for (int i = 0; i < 4; ++i)
#pragma unroll
        for (int j = 0; j < 4; ++j)
          acc[i][j] += xv[i].x * wv[j].x + xv[i].y * wv[j].y +
                       xv[i].z * wv[j].z + xv[i].w * wv[j].w;
    }
  }

#pragma unroll
  for (int i = 0; i < 4; ++i) {
    int grow = rowbase + tr * 4 + i;
    if (grow < nrows) {
#pragma unroll
      for (int j = 0; j < 4; ++j)
        out[(size_t)grow * 64 + tc + 16 * j] = acc[i][j];
    }
  }
}

// ---------------- edge aggregation: one wave per node, lane = feature ----------------

__global__ __launch_bounds__(256) void agg_k(
    const float* __restrict__ h, const float* __restrict__ dinv,
    const int* __restrict__ rowptr, const int* __restrict__ deg,
    const int* __restrict__ csr, const float* __restrict__ bias,
    float* __restrict__ out) {
  int n = blockIdx.x * 4 + (threadIdx.x >> 6);
  int lane = threadIdx.x & 63;
  if (n >= N_NODES) return;
  float dn = dinv[n];
  float acc = h[(size_t)n * 64 + lane] * dn * dn;  // self loop (norm 1/deg)
  int start = rowptr[n];
  int cnt = deg[n];
  for (int j0 = 0; j0 < cnt; j0 += 64) {
    int rem = cnt - j0;
    int m = rem < 64 ? rem : 64;
    int mysrc = 0; float myw = 0.f;
    if (lane < m) { mysrc = csr[start + j0 + lane]; myw = dinv[mysrc]; }
    for (int jj = 0; jj < m; ++jj) {
      int src = __shfl(mysrc, jj);
      float w = __shfl(myw, jj) * dn;
      acc += h[(size_t)src * 64 + lane] * w;
    }
  }
  out[(size_t)n * 64 + lane] = acc + bias[lane];
}

// ---------------- BatchNorm stats ----------------

__global__ __launch_bounds__(256) void bnstats_k(const float* __restrict__ h,
                                                 float* __restrict__ part) {
  int c = threadIdx.x & 63;
  int w = threadIdx.x >> 6;
  float s = 0.f, s2 = 0.f;
  for (int n = blockIdx.x * 4 + w; n < N_NODES; n += BN_BLOCKS * 4) {
    float v = h[(size_t)n * 64 + c];
    s += v; s2 += v * v;
  }
  __shared__ float ls[4][64], ls2[4][64];
  ls[w][c] = s; ls2[w][c] = s2;
  __syncthreads();
  if (w == 0) {
    s = ls[0][c] + ls[1][c] + ls[2][c] + ls[3][c];
    s2 = ls2[0][c] + ls2[1][c] + ls2[2][c] + ls2[3][c];
    part[blockIdx.x * 128 + c] = s;
    part[blockIdx.x * 128 + 64 + c] = s2;
  }
}

__global__ void bnfinal_k(const float* __restrict__ part,
                          const float* __restrict__ gamma, const float* __restrict__ beta,
                          float* __restrict__ scale, float* __restrict__ shift) {
  __shared__ float ls[4][64], ls2[4][64];
  int c = threadIdx.x & 63, q = threadIdx.x >> 6;
  float s = 0.f, s2 = 0.f;
  for (int b = q; b < BN_BLOCKS; b += 4) {
    s += part[b * 128 + c];
    s2 += part[b * 128 + 64 + c];
  }
  ls[q][c] = s; ls2[q][c] = s2;
  __syncthreads();
  if (q == 0) {
    s = ls[0][c] + ls[1][c] + ls[2][c] + ls[3][c];
    s2 = ls2[0][c] + ls2[1][c] + ls2[2][c] + ls2[3][c];
    float mean = s / (float)N_NODES;
    float var = s2 / (float)N_NODES - mean * mean;
    float sc = gamma[c] * rsqrtf(var + BN_EPS);
    scale[c] = sc;
    shift[c] = beta[c] - mean * sc;
  }
}

// ---------------- pooling (batch is sorted) ----------------

#define POOL_CHUNK 64
__global__ __launch_bounds__(64) void pool_k(
    const float* __restrict__ h, const float* __restrict__ scale,
    const float* __restrict__ shift, const int* __restrict__ batch,
    float* __restrict__ psum, float* __restrict__ pcnt) {
  int lane = threadIdx.x;
  int start = blockIdx.x * POOL_CHUNK;
  if (start >= N_NODES) return;
  int end = min(start + POOL_CHUNK, N_NODES);
  float sc = scale[lane], sh = shift[lane];
  float acc = 0.f, cnt = 0.f;
  int cur = batch[start];
  for (int n = start; n < end; ++n) {
    int g = batch[n];
    if (g != cur) {  // wave-uniform branch
      atomicAdd(&psum[cur * 64 + lane], acc);
      if (lane == 0) atomicAdd(&pcnt[cur], cnt);
      acc = 0.f; cnt = 0.f; cur = g;
    }
    acc += h[(size_t)n * 64 + lane] * sc + sh;
    cnt += 1.f;
  }
  atomicAdd(&psum[cur * 64 + lane], acc);
  if (lane == 0) atomicAdd(&pcnt[cur], cnt);
}

// ---------------- centroid classifier ----------------

__global__ void classify_k(const float* __restrict__ psum, const float* __restrict__ pcnt,
                           const float* __restrict__ cg, const float* __restrict__ cm,
                           const float* __restrict__ temp, float* __restrict__ out) {
  int g = blockIdx.x;
  int t = threadIdx.x;
  __shared__ float emb[64];
  __shared__ float dist[208];
  if (t < 64) emb[t] = psum[g * 64 + t] / fmaxf(pcnt[g], 1.0f);
  __syncthreads();
  if (t < 197) {
    const float* C = (t < 5) ? (cg + t * 64) : (cm + (t - 5) * 64);
    float d = 0.f;
#pragma unroll 8
    for (int k = 0; k < 64; ++k) {
      float df = emb[k] - C[k];
      d += df * df;
    }
    dist[t] = d;
  }
  __syncthreads();
  float tv = temp[0];
  if (t == 64) {
    float m = dist[0];
    for (int j = 1; j < 5; ++j) m = fminf(m, dist[j]);
    out[g * 65] = -m / tv;
  }
  if (t < 64) {
    float m = fminf(dist[5 + t * 3], fminf(dist[5 + t * 3 + 1], dist[5 + t * 3 + 2]));
    out[g * 65 + 1 + t] = -m / tv;
  }
}

// ---------------- launch ----------------

extern "C" void kernel_launch(void* const* d_in, const int* in_sizes, int n_in,
                              void* d_out, int out_size, void* d_ws, size_t ws_size,
                              hipStream_t stream) {
  const float* x   = (const float*)d_in[0];
  const int* ei    = (const int*)d_in[1];
  const int* batch = (const int*)d_in[2];
  const float* W1 = (const float*)d_in[3];  const float* b1 = (const float*)d_in[4];
  const float* g1 = (const float*)d_in[5];  const float* be1 = (const float*)d_in[6];
  const float* W2 = (const float*)d_in[7];  const float* b2 = (const float*)d_in[8];
  const float* g2 = (const float*)d_in[9];  const float* be2 = (const float*)d_in[10];
  const float* W3 = (const float*)d_in[11]; const float* b3 = (const float*)d_in[12];
  const float* g3 = (const float*)d_in[13]; const float* be3 = (const float*)d_in[14];
  const float* cg = (const float*)d_in[15];
  const float* cm = (const float*)d_in[16];
  const float* temp = (const float*)d_in[17];
  float* out = (float*)d_out;

  char* ws = (char*)d_ws;
  size_t off = 0;
  auto alloc = [&](size_t bytes) -> void* {
    void* p = ws + off;
    off = (off + bytes + 255) & ~(size_t)255;
    return p;
  };
  int* deg     = (int*)alloc((size_t)N_NODES * 4);
  float* dinv  = (float*)alloc((size_t)N_NODES * 4);
  int* rowptr  = (int*)alloc((size_t)N_NODES * 4);
  int* cursor  = (int*)alloc((size_t)N_NODES * 4);
  int* bsum    = (int*)alloc(1024);
  int* csr     = (int*)alloc((size_t)N_EDGES * 4);
  float* hA    = (float*)alloc((size_t)N_NODES * 64 * 4);
  float* hB    = (float*)alloc((size_t)N_NODES * 64 * 4);
  float* part  = (float*)alloc((size_t)BN_BLOCKS * 128 * 4);
  float* scale = (float*)alloc(64 * 4);
  float* shift = (float*)alloc(64 * 4);
  float* psum  = (float*)alloc(64 * 64 * 4);
  float* pcnt  = (float*)alloc(64 * 4);

  hipMemsetAsync(deg, 0, (size_t)N_NODES * 4, stream);
  hipMemsetAsync(cursor, 0, (size_t)N_NODES * 4, stream);
  hipMemsetAsync(psum, 0, 64 * 64 * 4, stream);
  hipMemsetAsync(pcnt, 0, 64 * 4, stream);

  const int NB_NODE = (N_NODES + 255) / 256;     // 391
  const int NB_EDGE = N_EDGES / 256;             // 12500
  const int NB_GEMM = (N_NODES + 63) / 64;       // 1563
  const int NB_AGG  = (N_NODES + 3) / 4;         // 25000
  const int NB_POOL = (N_NODES + POOL_CHUNK - 1) / POOL_CHUNK;  // 1563

  count_deg_k<<<NB_EDGE, 256, 0, stream>>>(ei, deg);
  dinv_k<<<NB_NODE, 256, 0, stream>>>(deg, dinv);
  scan_a_k<<<NBLK_SCAN, 256, 0, stream>>>(deg, bsum);
  scan_b_k<<<1, 128, 0, stream>>>(bsum);
  scan_c_k<<<NBLK_SCAN, 256, 0, stream>>>(deg, bsum, rowptr);
  fill_csr_k<<<NB_EDGE, 256, 0, stream>>>(ei, rowptr, cursor, csr);

  // layer 1
  gemm_k<IN_DIM, false, false><<<NB_GEMM, 256, 0, stream>>>(x, W1, nullptr, nullptr, hA, N_NODES);
  agg_k<<<NB_AGG, 256, 0, stream>>>(hA, dinv, rowptr, deg, csr, b1, hB);
  bnstats_k<<<BN_BLOCKS, 256, 0, stream>>>(hB, part);
  bnfinal_k<<<1, 256, 0, stream>>>(part, g1, be1, scale, shift);

  // layer 2 (BN1+ReLU applied on GEMM input load)
  gemm_k<HID, true, true><<<NB_GEMM, 256, 0, stream>>>(hB, W2, scale, shift, hA, N_NODES);
  agg_k<<<NB_AGG, 256, 0, stream>>>(hA, dinv, rowptr, deg, csr, b2, hB);
  bnstats_k<<<BN_BLOCKS, 256, 0, stream>>>(hB, part);
  bnfinal_k<<<1, 256, 0, stream>>>(part, g2, be2, scale, shift);

  // layer 3
  gemm_k<HID, true, true><<<NB_GEMM, 256, 0, stream>>>(hB, W3, scale, shift, hA, N_NODES);
  agg_k<<<NB_AGG, 256, 0, stream>>>(hA, dinv, rowptr, deg, csr, b3, hB);
  bnstats_k<<<BN_BLOCKS, 256, 0, stream>>>(hB, part);
  bnfinal_k<<<1, 256, 0, stream>>>(part, g3, be3, scale, shift);

  // pool (BN3, no ReLU, applied here) + classify
  pool_k<<<NB_POOL, 64, 0, stream>>>(hB, scale, shift, batch, psum, pcnt);
  classify_k<<<N_GRAPHS, 256, 0, stream>>>(psum, pcnt, cg, cm, temp, out);
}